// Round 8
// baseline (537.680 us; speedup 1.0000x reference)
//
#include <hip/hip_runtime.h>

#define NB 512
#define NT 1024
#define NK 48
#define NEGV -10000.0f
#define S_START 46
#define S_END 47
#define NCH 64            // 16-step windows (chunks)
#define CLEN 16

__device__ __forceinline__ float rfl_f32(float x) {
    return __int_as_float(__builtin_amdgcn_readfirstlane(__float_as_int(x)));
}
// exact broadcast of lane k's value to all lanes (VALU, no LDS pipe use)
__device__ __forceinline__ float rlane_f32(float x, int k) {
    return __int_as_float(__builtin_amdgcn_readlane(__float_as_int(x), k));
}

// 4 waves/block, lockstep-barrier pipeline (66 __syncthreads per wave —
// identical barrier count on every wave; deadlock structurally impossible).
// w0: CRF forward. w1: value-only Viterbi sweep + checkpoint ring.
// w2/w3: replay chunk c (even/odd) over windows c,c+1 with the FULL argmax
// (bit-identical arithmetic -> identical backpointers); replay broadcast is
// register+readlane (no LDS pipe traffic). w1 epilogue: chase + expansion.
// Feat loads for w0/w1 are window-level register double-buffered so no
// global loads are in flight at the barriers (no vmcnt(0) drain stalls).
extern "C" __global__ __launch_bounds__(256, 1)
void crf_fused(const float* __restrict__ feats, const float* __restrict__ trans,
               float* __restrict__ out)
{
    __shared__ unsigned char bp[NT * NK];        // 48 KB backpointers
    __shared__ float ckpt[4 * NK];               // 4-slot chunk-entry ring
    __shared__ unsigned char comp[NCH * NK];     // 3 KB composed chunk maps
    __shared__ unsigned char boundary[NCH];
    __shared__ float eabuf[64];                  // fwd broadcast
    __shared__ float vbuf1[64];                  // sweep broadcast

    const int b = blockIdx.x;
    const int wave = threadIdx.x >> 6;
    const int lane = threadIdx.x & 63;
    const bool act = lane < NK;
    const int LL = act ? lane : (NK - 1);        // lanes 48..63 mirror 47
    const float* f = feats + (size_t)b * NT * NK;
    const float* fb = f + LL;

    float tEnd = NEGV;
    if (act && lane != S_END) tEnd = trans[S_END * NK + lane];

    if (wave == 0) {
        // ---------------- forward: alpha' = Muni + u; u anchored at lane 0
        float Erow[NK];
        {
            const bool rowdead = (lane == S_START);
            const float4* r4 = (const float4*)(trans + LL * NK);
            #pragma unroll
            for (int q = 0; q < NK / 4; ++q) {
                float4 r = r4[q];
                const int c = 4 * q;
                Erow[c + 0] = (rowdead || c + 0 == S_END) ? 0.0f : __expf(r.x);
                Erow[c + 1] = (rowdead || c + 1 == S_END) ? 0.0f : __expf(r.y);
                Erow[c + 2] = (rowdead || c + 2 == S_END) ? 0.0f : __expf(r.z);
                Erow[c + 3] = (rowdead || c + 3 == S_END) ? 0.0f : __expf(r.w);
            }
        }
        float u = (lane == S_START) ? 0.0f : NEGV;
        float Muni = 0.0f;
        eabuf[lane] = __expf(u);
        __builtin_amdgcn_wave_barrier();

        auto fstep = [&](float fc) {
            float ea[NK];
            {
                const float4* e4 = (const float4*)eabuf;
                #pragma unroll
                for (int q = 0; q < NK / 4; ++q) {
                    float4 r = e4[q];
                    ea[4 * q + 0] = r.x; ea[4 * q + 1] = r.y;
                    ea[4 * q + 2] = r.z; ea[4 * q + 3] = r.w;
                }
            }
            float a0 = 0.f, a1 = 0.f, a2 = 0.f, a3 = 0.f;
            #pragma unroll
            for (int p = 0; p < NK; p += 4) {
                a0 = fmaf(Erow[p + 0], ea[p + 0], a0);
                a1 = fmaf(Erow[p + 1], ea[p + 1], a1);
                a2 = fmaf(Erow[p + 2], ea[p + 2], a2);
                a3 = fmaf(Erow[p + 3], ea[p + 3], a3);
            }
            float acc = (a0 + a1) + (a2 + a3);
            float w = __logf(acc) + fc;
            float dM = rfl_f32(w);
            Muni += dM;
            u = w - dM;
            __builtin_amdgcn_wave_barrier();
            eabuf[lane] = __expf(u);
            __builtin_amdgcn_wave_barrier();
        };

        float fcur[CLEN], fnext[CLEN];
        #pragma unroll
        for (int i = 0; i < CLEN; ++i) fcur[i] = fb[i * NK];
        __syncthreads();                                     // B0
        for (int it = 0; it <= NCH; ++it) {
            if (it < NCH) {
                #pragma unroll
                for (int i = 0; i < CLEN; ++i) {             // next-window loads,
                    int t = (it + 1) * CLEN + i;             // issued at window start
                    if (t >= NT) t = NT - 1;
                    fnext[i] = fb[t * NK];
                }
                #pragma unroll
                for (int i = 0; i < CLEN; ++i) fstep(fcur[i]);
                #pragma unroll
                for (int i = 0; i < CLEN; ++i) fcur[i] = fnext[i];
            }
            __syncthreads();                                 // B1..B65
        }
        float x = act ? (u + tEnd) : -INFINITY;
        float M2 = x;
        #pragma unroll
        for (int off = 32; off >= 1; off >>= 1)
            M2 = fmaxf(M2, __shfl_xor(M2, off, 64));
        float e = __expf(x - M2);
        #pragma unroll
        for (int off = 32; off >= 1; off >>= 1)
            e += __shfl_xor(e, off, 64);
        if (lane == 0) out[b] = Muni + M2 + __logf(e);
    } else if (wave == 1) {
        // ---------------- producer: value-only sweep + checkpoint ring
        float trow[NK];
        {
            const bool rowdead = (lane == S_START);
            const float4* r4 = (const float4*)(trans + LL * NK);
            #pragma unroll
            for (int q = 0; q < NK / 4; ++q) {
                float4 r = r4[q];
                const int c = 4 * q;
                trow[c + 0] = (rowdead || c + 0 == S_END) ? NEGV : r.x;
                trow[c + 1] = (rowdead || c + 1 == S_END) ? NEGV : r.y;
                trow[c + 2] = (rowdead || c + 2 == S_END) ? NEGV : r.z;
                trow[c + 3] = (rowdead || c + 3 == S_END) ? NEGV : r.w;
            }
        }
        float v = (lane == S_START) ? 0.0f : NEGV;
        vbuf1[lane] = v;
        if (act) ckpt[0 * NK + lane] = v;                    // chunk-0 entry
        __builtin_amdgcn_wave_barrier();

        auto vstep = [&](float fc) {
            float s[NK];
            {
                const float4* v4 = (const float4*)vbuf1;
                #pragma unroll
                for (int q = 0; q < NK / 4; ++q) {
                    float4 r = v4[q];
                    s[4 * q + 0] = r.x + trow[4 * q + 0];
                    s[4 * q + 1] = r.y + trow[4 * q + 1];
                    s[4 * q + 2] = r.z + trow[4 * q + 2];
                    s[4 * q + 3] = r.w + trow[4 * q + 3];
                }
            }
            float m16[16];
            #pragma unroll
            for (int i = 0; i < 16; ++i)
                m16[i] = fmaxf(fmaxf(s[3 * i], s[3 * i + 1]), s[3 * i + 2]);
            float m6[6];
            #pragma unroll
            for (int i = 0; i < 5; ++i)
                m6[i] = fmaxf(fmaxf(m16[3 * i], m16[3 * i + 1]), m16[3 * i + 2]);
            m6[5] = m16[15];
            float best = fmaxf(fmaxf(fmaxf(m6[0], m6[1]), m6[2]),
                               fmaxf(fmaxf(m6[3], m6[4]), m6[5]));
            v = best + fc;                                   // +feat after max
            __builtin_amdgcn_wave_barrier();
            vbuf1[lane] = v;
            __builtin_amdgcn_wave_barrier();
        };

        float fcur[CLEN], fnext[CLEN];
        #pragma unroll
        for (int i = 0; i < CLEN; ++i) fcur[i] = fb[i * NK];
        int last = 0;
        __syncthreads();                                     // B0
        for (int it = 0; it <= NCH; ++it) {
            if (it < NCH) {
                #pragma unroll
                for (int i = 0; i < CLEN; ++i) {
                    int t = (it + 1) * CLEN + i;
                    if (t >= NT) t = NT - 1;
                    fnext[i] = fb[t * NK];
                }
                #pragma unroll
                for (int i = 0; i < CLEN; ++i) vstep(fcur[i]);
                #pragma unroll
                for (int i = 0; i < CLEN; ++i) fcur[i] = fnext[i];
                // v is now the entry state of chunk it+1 -> ring slot
                if (act && it + 1 < NCH) ckpt[((it + 1) & 3) * NK + lane] = v;
            } else {
                // termination: first-occurrence argmax of v + trans[END]
                float xv = act ? (v + tEnd) : -INFINITY;
                int idx = act ? lane : 63;
                float val = xv;
                #pragma unroll
                for (int off = 32; off >= 1; off >>= 1) {
                    float ov = __shfl_xor(val, off, 64);
                    int   oi = __shfl_xor(idx, off, 64);
                    if (ov > val || (ov == val && oi < idx)) { val = ov; idx = oi; }
                }
                if (lane == 0) out[NB + b] = val;
                last = idx;
            }
            __syncthreads();                                 // B1..B65
        }
        // epilogue: chase + expansion (bp/comp complete after final barrier)
        if (lane == 0) {
            int tag = last;
            for (int l = NCH - 1; l >= 0; --l) {
                boundary[l] = (unsigned char)tag;
                tag = comp[l * NK + tag];
            }
        }
        __builtin_amdgcn_wave_barrier();
        int tag = boundary[lane];                            // lane = chunk
        float* pout = out + 2 * NB + (size_t)b * NT;
        const int tbase = lane * CLEN;
        for (int i = CLEN - 1; i >= 0; --i) {
            pout[tbase + i] = (float)tag;
            tag = bp[(tbase + i) * NK + tag];
        }
    } else {
        // ---------------- consumers: replay chunk c over windows c, c+1.
        // State vl lives in a lane-local register; broadcast via readlane
        // (exact) -> zero LDS-pipe traffic in the replay inner loop.
        const int w = wave - 2;                              // 0: even, 1: odd
        float trow[NK];
        {
            const bool rowdead = (lane == S_START);
            const float4* r4 = (const float4*)(trans + LL * NK);
            #pragma unroll
            for (int q = 0; q < NK / 4; ++q) {
                float4 r = r4[q];
                const int c = 4 * q;
                trow[c + 0] = (rowdead || c + 0 == S_END) ? NEGV : r.x;
                trow[c + 1] = (rowdead || c + 1 == S_END) ? NEGV : r.y;
                trow[c + 2] = (rowdead || c + 2 == S_END) ? NEGV : r.z;
                trow[c + 3] = (rowdead || c + 3 == S_END) ? NEGV : r.w;
            }
        }
        const int big = 63;
        int bpl[8], bph[8];
        float vl = 0.0f;                                     // in-progress chunk state

        auto replay8 = [&](int c, int base, int* bparr8) {
            const float* fbc = fb + (size_t)c * CLEN * NK;
            unsigned char* bpc = bp + (size_t)c * CLEN * NK;
            float fv[8];
            #pragma unroll
            for (int i = 0; i < 8; ++i) fv[i] = fbc[(base + i) * NK];
            #pragma unroll
            for (int i = 0; i < 8; ++i) {
                float s[NK];
                #pragma unroll
                for (int p = 0; p < NK; p += 4) {
                    s[p + 0] = rlane_f32(vl, p + 0) + trow[p + 0];
                    s[p + 1] = rlane_f32(vl, p + 1) + trow[p + 1];
                    s[p + 2] = rlane_f32(vl, p + 2) + trow[p + 2];
                    s[p + 3] = rlane_f32(vl, p + 3) + trow[p + 3];
                }
                float m16[16];
                #pragma unroll
                for (int j = 0; j < 16; ++j)
                    m16[j] = fmaxf(fmaxf(s[3 * j], s[3 * j + 1]), s[3 * j + 2]);
                float m6[6];
                #pragma unroll
                for (int j = 0; j < 5; ++j)
                    m6[j] = fmaxf(fmaxf(m16[3 * j], m16[3 * j + 1]), m16[3 * j + 2]);
                m6[5] = m16[15];
                float best = fmaxf(fmaxf(fmaxf(m6[0], m6[1]), m6[2]),
                                   fmaxf(fmaxf(m6[3], m6[4]), m6[5]));
                int ix[NK];
                #pragma unroll
                for (int p = 0; p < NK; ++p)
                    ix[p] = (s[p] != best) ? big : p;
                int n16[16];
                #pragma unroll
                for (int j = 0; j < 16; ++j)
                    n16[j] = min(min(ix[3 * j], ix[3 * j + 1]), ix[3 * j + 2]);
                int n6[6];
                #pragma unroll
                for (int j = 0; j < 5; ++j)
                    n6[j] = min(min(n16[3 * j], n16[3 * j + 1]), n16[3 * j + 2]);
                n6[5] = n16[15];
                int bi = min(min(min(n6[0], n6[1]), n6[2]),
                             min(min(n6[3], n6[4]), n6[5]));

                bparr8[i] = bi;
                bpc[(base + i) * NK + LL] = (unsigned char)bi;
                vl = best + fv[i];                           // +feat after argmax
            }
        };

        __syncthreads();                                     // B0
        for (int it = 0; it <= NCH; ++it) {
            if ((it & 1) == w && it < NCH) {
                // start chunk c = it (ckpt[c] published during window it-1)
                vl = ckpt[(it & 3) * NK + LL];
                replay8(it, 0, bpl);
            } else if ((it & 1) != w && it >= 1) {
                // finish chunk c = it-1, then compose its tag-map
                const int c = it - 1;
                replay8(c, 8, bph);
                int tag = act ? lane : 0;
                #pragma unroll
                for (int i = 7; i >= 0; --i)
                    tag = __builtin_amdgcn_ds_bpermute(tag << 2, bph[i]);
                #pragma unroll
                for (int i = 7; i >= 0; --i)
                    tag = __builtin_amdgcn_ds_bpermute(tag << 2, bpl[i]);
                if (act) comp[c * NK + lane] = (unsigned char)tag;
            }
            __syncthreads();                                 // B1..B65
        }
    }
}

extern "C" void kernel_launch(void* const* d_in, const int* in_sizes, int n_in,
                              void* d_out, int out_size, void* d_ws, size_t ws_size,
                              hipStream_t stream) {
    (void)in_sizes; (void)n_in; (void)d_ws; (void)ws_size; (void)out_size;
    const float* feats = (const float*)d_in[0];
    const float* trans = (const float*)d_in[1];
    float* out = (float*)d_out;
    crf_fused<<<dim3(NB), dim3(256), 0, stream>>>(feats, trans, out);
}

// Round 9
// 493.904 us; speedup vs baseline: 1.0886x; 1.0886x over previous
//
#include <hip/hip_runtime.h>

#define NB 512
#define NT 1024
#define NK 48
#define NEGV -10000.0f
#define S_START 46
#define S_END 47
#define NCH 64            // 16-step windows (chunks)
#define CLEN 16

__device__ __forceinline__ float rfl_f32(float x) {
    return __int_as_float(__builtin_amdgcn_readfirstlane(__float_as_int(x)));
}

// 4 waves/block, lockstep-barrier pipeline (66 __syncthreads per wave —
// identical barrier count on every wave; deadlock structurally impossible).
// w0: CRF forward. w1: value-only Viterbi sweep, publishes chunk-entry
// checkpoints to a 4-slot LDS ring. w2/w3: replay chunk c (even/odd) over
// windows c,c+1 with the FULL argmax (bit-identical arithmetic ->
// identical backpointers), write bp + composed maps. w1 epilogue:
// boundary chase + path expansion.
// R9 change vs R7: replay argmax leaf level uses a first-occurrence
// chained select (6 instr/group) instead of masked-index + min tree
// (8 instr/group) — exact same result, ~16% less replay VALU issue.
// (R8 lesson, 3x-confirmed: NEVER swap LDS broadcast for readlane VALU.)
extern "C" __global__ __launch_bounds__(256, 1)
void crf_fused(const float* __restrict__ feats, const float* __restrict__ trans,
               float* __restrict__ out)
{
    __shared__ unsigned char bp[NT * NK];        // 48 KB backpointers
    __shared__ float ckpt[4 * NK];               // 4-slot chunk-entry ring
    __shared__ unsigned char comp[NCH * NK];     // 3 KB composed chunk maps
    __shared__ unsigned char boundary[NCH];
    __shared__ float eabuf[64];                  // fwd broadcast
    __shared__ float vbuf1[64];                  // sweep broadcast
    __shared__ float vbufw[2][64];               // replay broadcast per wave

    const int b = blockIdx.x;
    const int wave = threadIdx.x >> 6;
    const int lane = threadIdx.x & 63;
    const bool act = lane < NK;
    const int LL = act ? lane : (NK - 1);        // lanes 48..63 mirror 47
    const float* f = feats + (size_t)b * NT * NK;
    const float* fb = f + LL;

    float tEnd = NEGV;
    if (act && lane != S_END) tEnd = trans[S_END * NK + lane];

    if (wave == 0) {
        // ---------------- forward: alpha' = Muni + u; u anchored at lane 0
        float Erow[NK];
        {
            const bool rowdead = (lane == S_START);
            const float4* r4 = (const float4*)(trans + LL * NK);
            #pragma unroll
            for (int q = 0; q < NK / 4; ++q) {
                float4 r = r4[q];
                const int c = 4 * q;
                Erow[c + 0] = (rowdead || c + 0 == S_END) ? 0.0f : __expf(r.x);
                Erow[c + 1] = (rowdead || c + 1 == S_END) ? 0.0f : __expf(r.y);
                Erow[c + 2] = (rowdead || c + 2 == S_END) ? 0.0f : __expf(r.z);
                Erow[c + 3] = (rowdead || c + 3 == S_END) ? 0.0f : __expf(r.w);
            }
        }
        float u = (lane == S_START) ? 0.0f : NEGV;
        float Muni = 0.0f;
        eabuf[lane] = __expf(u);
        __builtin_amdgcn_wave_barrier();
        float fr0 = fb[0 * NK], fr1 = fb[1 * NK], fr2 = fb[2 * NK], fr3 = fb[3 * NK];

        auto fstep = [&](float fc) {
            float ea[NK];
            {
                const float4* e4 = (const float4*)eabuf;
                #pragma unroll
                for (int q = 0; q < NK / 4; ++q) {
                    float4 r = e4[q];
                    ea[4 * q + 0] = r.x; ea[4 * q + 1] = r.y;
                    ea[4 * q + 2] = r.z; ea[4 * q + 3] = r.w;
                }
            }
            float a0 = 0.f, a1 = 0.f, a2 = 0.f, a3 = 0.f;
            #pragma unroll
            for (int p = 0; p < NK; p += 4) {
                a0 = fmaf(Erow[p + 0], ea[p + 0], a0);
                a1 = fmaf(Erow[p + 1], ea[p + 1], a1);
                a2 = fmaf(Erow[p + 2], ea[p + 2], a2);
                a3 = fmaf(Erow[p + 3], ea[p + 3], a3);
            }
            float acc = (a0 + a1) + (a2 + a3);
            float w = __logf(acc) + fc;
            float dM = rfl_f32(w);
            Muni += dM;
            u = w - dM;
            __builtin_amdgcn_wave_barrier();
            eabuf[lane] = __expf(u);
            __builtin_amdgcn_wave_barrier();
        };

        __syncthreads();                                     // B0
        for (int it = 0; it <= NCH; ++it) {
            if (it < NCH) {
                #pragma unroll
                for (int g = 0; g < 4; ++g) {
                    const int t = it * CLEN + 4 * g;
                    { float fc = fr0; int nr = (t + 4 < NT) ? t + 4 : NT - 1; fr0 = fb[nr * NK]; fstep(fc); }
                    { float fc = fr1; int nr = (t + 5 < NT) ? t + 5 : NT - 1; fr1 = fb[nr * NK]; fstep(fc); }
                    { float fc = fr2; int nr = (t + 6 < NT) ? t + 6 : NT - 1; fr2 = fb[nr * NK]; fstep(fc); }
                    { float fc = fr3; int nr = (t + 7 < NT) ? t + 7 : NT - 1; fr3 = fb[nr * NK]; fstep(fc); }
                }
            }
            __syncthreads();                                 // B1..B65
        }
        float x = act ? (u + tEnd) : -INFINITY;
        float M2 = x;
        #pragma unroll
        for (int off = 32; off >= 1; off >>= 1)
            M2 = fmaxf(M2, __shfl_xor(M2, off, 64));
        float e = __expf(x - M2);
        #pragma unroll
        for (int off = 32; off >= 1; off >>= 1)
            e += __shfl_xor(e, off, 64);
        if (lane == 0) out[b] = Muni + M2 + __logf(e);
    } else if (wave == 1) {
        // ---------------- producer: value-only sweep + checkpoint ring
        float trow[NK];
        {
            const bool rowdead = (lane == S_START);
            const float4* r4 = (const float4*)(trans + LL * NK);
            #pragma unroll
            for (int q = 0; q < NK / 4; ++q) {
                float4 r = r4[q];
                const int c = 4 * q;
                trow[c + 0] = (rowdead || c + 0 == S_END) ? NEGV : r.x;
                trow[c + 1] = (rowdead || c + 1 == S_END) ? NEGV : r.y;
                trow[c + 2] = (rowdead || c + 2 == S_END) ? NEGV : r.z;
                trow[c + 3] = (rowdead || c + 3 == S_END) ? NEGV : r.w;
            }
        }
        float v = (lane == S_START) ? 0.0f : NEGV;
        vbuf1[lane] = v;
        if (act) ckpt[0 * NK + lane] = v;                    // chunk-0 entry
        __builtin_amdgcn_wave_barrier();
        float fr0 = fb[0 * NK], fr1 = fb[1 * NK], fr2 = fb[2 * NK], fr3 = fb[3 * NK];

        auto vstep = [&](float fc) {
            float s[NK];
            {
                const float4* v4 = (const float4*)vbuf1;
                #pragma unroll
                for (int q = 0; q < NK / 4; ++q) {
                    float4 r = v4[q];
                    s[4 * q + 0] = r.x + trow[4 * q + 0];
                    s[4 * q + 1] = r.y + trow[4 * q + 1];
                    s[4 * q + 2] = r.z + trow[4 * q + 2];
                    s[4 * q + 3] = r.w + trow[4 * q + 3];
                }
            }
            float m16[16];
            #pragma unroll
            for (int i = 0; i < 16; ++i)
                m16[i] = fmaxf(fmaxf(s[3 * i], s[3 * i + 1]), s[3 * i + 2]);
            float m6[6];
            #pragma unroll
            for (int i = 0; i < 5; ++i)
                m6[i] = fmaxf(fmaxf(m16[3 * i], m16[3 * i + 1]), m16[3 * i + 2]);
            m6[5] = m16[15];
            float best = fmaxf(fmaxf(fmaxf(m6[0], m6[1]), m6[2]),
                               fmaxf(fmaxf(m6[3], m6[4]), m6[5]));
            v = best + fc;                                   // +feat after max
            __builtin_amdgcn_wave_barrier();
            vbuf1[lane] = v;
            __builtin_amdgcn_wave_barrier();
        };

        int last = 0;
        __syncthreads();                                     // B0
        for (int it = 0; it <= NCH; ++it) {
            if (it < NCH) {
                #pragma unroll
                for (int g = 0; g < 4; ++g) {
                    const int t = it * CLEN + 4 * g;
                    { float fc = fr0; int nr = (t + 4 < NT) ? t + 4 : NT - 1; fr0 = fb[nr * NK]; vstep(fc); }
                    { float fc = fr1; int nr = (t + 5 < NT) ? t + 5 : NT - 1; fr1 = fb[nr * NK]; vstep(fc); }
                    { float fc = fr2; int nr = (t + 6 < NT) ? t + 6 : NT - 1; fr2 = fb[nr * NK]; vstep(fc); }
                    { float fc = fr3; int nr = (t + 7 < NT) ? t + 7 : NT - 1; fr3 = fb[nr * NK]; vstep(fc); }
                }
                // v is now the entry state of chunk it+1 -> ring slot
                if (act && it + 1 < NCH) ckpt[((it + 1) & 3) * NK + lane] = v;
            } else {
                // termination: first-occurrence argmax of v + trans[END]
                float xv = act ? (v + tEnd) : -INFINITY;
                int idx = act ? lane : 63;
                float val = xv;
                #pragma unroll
                for (int off = 32; off >= 1; off >>= 1) {
                    float ov = __shfl_xor(val, off, 64);
                    int   oi = __shfl_xor(idx, off, 64);
                    if (ov > val || (ov == val && oi < idx)) { val = ov; idx = oi; }
                }
                if (lane == 0) out[NB + b] = val;
                last = idx;
            }
            __syncthreads();                                 // B1..B65
        }
        // epilogue: chase + expansion (bp/comp complete after final barrier)
        if (lane == 0) {
            int tag = last;
            for (int l = NCH - 1; l >= 0; --l) {
                boundary[l] = (unsigned char)tag;
                tag = comp[l * NK + tag];
            }
        }
        __builtin_amdgcn_wave_barrier();
        int tag = boundary[lane];                            // lane = chunk
        float* pout = out + 2 * NB + (size_t)b * NT;
        const int tbase = lane * CLEN;
        for (int i = CLEN - 1; i >= 0; --i) {
            pout[tbase + i] = (float)tag;
            tag = bp[(tbase + i) * NK + tag];
        }
    } else {
        // ---------------- consumers: replay chunk c over windows c, c+1
        const int w = wave - 2;                              // 0: even, 1: odd
        float trow[NK];
        {
            const bool rowdead = (lane == S_START);
            const float4* r4 = (const float4*)(trans + LL * NK);
            #pragma unroll
            for (int q = 0; q < NK / 4; ++q) {
                float4 r = r4[q];
                const int c = 4 * q;
                trow[c + 0] = (rowdead || c + 0 == S_END) ? NEGV : r.x;
                trow[c + 1] = (rowdead || c + 1 == S_END) ? NEGV : r.y;
                trow[c + 2] = (rowdead || c + 2 == S_END) ? NEGV : r.z;
                trow[c + 3] = (rowdead || c + 3 == S_END) ? NEGV : r.w;
            }
        }
        float* vbw = vbufw[w];
        const int big = 63;
        int bpl[8], bph[8];

        // 8 replay steps [base, base+8) of chunk c; bparr8 statically indexed
        auto replay8 = [&](int c, int base, int* bparr8) {
            const float* fbc = fb + (size_t)c * CLEN * NK;
            unsigned char* bpc = bp + (size_t)c * CLEN * NK;
            float fv[8];
            #pragma unroll
            for (int i = 0; i < 8; ++i) fv[i] = fbc[(base + i) * NK];
            #pragma unroll
            for (int i = 0; i < 8; ++i) {
                float s[NK];
                {
                    const float4* v4 = (const float4*)vbw;
                    #pragma unroll
                    for (int q = 0; q < NK / 4; ++q) {
                        float4 r = v4[q];
                        s[4 * q + 0] = r.x + trow[4 * q + 0];
                        s[4 * q + 1] = r.y + trow[4 * q + 1];
                        s[4 * q + 2] = r.z + trow[4 * q + 2];
                        s[4 * q + 3] = r.w + trow[4 * q + 3];
                    }
                }
                float m16[16];
                #pragma unroll
                for (int j = 0; j < 16; ++j)
                    m16[j] = fmaxf(fmaxf(s[3 * j], s[3 * j + 1]), s[3 * j + 2]);
                float m6[6];
                #pragma unroll
                for (int j = 0; j < 5; ++j)
                    m6[j] = fmaxf(fmaxf(m16[3 * j], m16[3 * j + 1]), m16[3 * j + 2]);
                m6[5] = m16[15];
                float best = fmaxf(fmaxf(fmaxf(m6[0], m6[1]), m6[2]),
                                   fmaxf(fmaxf(m6[3], m6[4]), m6[5]));
                // first-occurrence argmax: chained select per 3-wide group
                // (exact: == min-of-masked-indices since indices ascend)
                int n16[16];
                #pragma unroll
                for (int j = 0; j < 16; ++j) {
                    int r = (s[3 * j + 2] == best) ? 3 * j + 2 : big;
                    r = (s[3 * j + 1] == best) ? 3 * j + 1 : r;
                    r = (s[3 * j + 0] == best) ? 3 * j + 0 : r;
                    n16[j] = r;
                }
                int n6[6];
                #pragma unroll
                for (int j = 0; j < 5; ++j)
                    n6[j] = min(min(n16[3 * j], n16[3 * j + 1]), n16[3 * j + 2]);
                n6[5] = n16[15];
                int bi = min(min(min(n6[0], n6[1]), n6[2]),
                             min(min(n6[3], n6[4]), n6[5]));

                bparr8[i] = bi;
                bpc[(base + i) * NK + LL] = (unsigned char)bi;
                float vn = best + fv[i];                     // +feat after argmax
                __builtin_amdgcn_wave_barrier();
                vbw[lane] = vn;
                __builtin_amdgcn_wave_barrier();
            }
        };

        __syncthreads();                                     // B0
        for (int it = 0; it <= NCH; ++it) {
            if ((it & 1) == w && it < NCH) {
                // start chunk c = it (ckpt[c] published during window it-1)
                vbw[lane] = ckpt[(it & 3) * NK + LL];
                __builtin_amdgcn_wave_barrier();
                replay8(it, 0, bpl);
            } else if ((it & 1) != w && it >= 1) {
                // finish chunk c = it-1, then compose its tag-map
                const int c = it - 1;
                replay8(c, 8, bph);
                int tag = act ? lane : 0;
                #pragma unroll
                for (int i = 7; i >= 0; --i)
                    tag = __builtin_amdgcn_ds_bpermute(tag << 2, bph[i]);
                #pragma unroll
                for (int i = 7; i >= 0; --i)
                    tag = __builtin_amdgcn_ds_bpermute(tag << 2, bpl[i]);
                if (act) comp[c * NK + lane] = (unsigned char)tag;
            }
            __syncthreads();                                 // B1..B65
        }
    }
}

extern "C" void kernel_launch(void* const* d_in, const int* in_sizes, int n_in,
                              void* d_out, int out_size, void* d_ws, size_t ws_size,
                              hipStream_t stream) {
    (void)in_sizes; (void)n_in; (void)d_ws; (void)ws_size; (void)out_size;
    const float* feats = (const float*)d_in[0];
    const float* trans = (const float*)d_in[1];
    float* out = (float*)d_out;
    crf_fused<<<dim3(NB), dim3(256), 0, stream>>>(feats, trans, out);
}

// Round 10
// 484.409 us; speedup vs baseline: 1.1100x; 1.0196x over previous
//
#include <hip/hip_runtime.h>

#define NB 512
#define NT 1024
#define NK 48
#define NEGV -10000.0f
#define S_START 46
#define S_END 47
#define NCH 32            // 32-step windows (chunks)
#define CLEN 32

__device__ __forceinline__ float rfl_f32(float x) {
    return __int_as_float(__builtin_amdgcn_readfirstlane(__float_as_int(x)));
}

// 4 waves/block, lockstep-barrier pipeline (34 __syncthreads per wave —
// identical count on every wave; deadlock structurally impossible).
// role0: CRF forward in the EXP DOMAIN: state ea[n]=exp(alpha[n]-M);
//   per-step renorm is an EXACT power-of-two from lane-0's exponent bits
//   (readfirstlane + SALU) — no log/exp on the serial chain; emission
//   folded in as nv=acc*exp(feat) with exp computed off-chain from the
//   4-step-early prefetch. logZ = Etot*ln2 + final logsumexp.
// role1: value-only Viterbi sweep + 4-slot checkpoint ring + epilogue.
// role2/3: replay chunk c (c%2==role-2) over windows c,c+1, 16 steps each,
//   FULL argmax (bit-identical -> identical backpointers), bp + comp.
// Roles rotate with blockIdx ((wave+b)&3) so co-resident blocks put
// different roles on the same SIMD (stall/issue mixing).
extern "C" __global__ __launch_bounds__(256, 1)
void crf_fused(const float* __restrict__ feats, const float* __restrict__ trans,
               float* __restrict__ out)
{
    __shared__ unsigned char bp[NT * NK];        // 48 KB backpointers
    __shared__ float ckpt[4 * NK];               // 4-slot chunk-entry ring
    __shared__ unsigned char comp[NCH * NK];     // composed chunk maps
    __shared__ unsigned char boundary[NCH];
    __shared__ float eabuf[64];                  // fwd broadcast
    __shared__ float vbuf1[64];                  // sweep broadcast
    __shared__ float vbufw[2][64];               // replay broadcast per wave

    const int b = blockIdx.x;
    const int wave = threadIdx.x >> 6;
    const int role = (wave + b) & 3;
    const int lane = threadIdx.x & 63;
    const bool act = lane < NK;
    const int LL = act ? lane : (NK - 1);        // lanes 48..63 mirror 47
    const float* f = feats + (size_t)b * NT * NK;
    const float* fb = f + LL;

    float tEnd = NEGV;
    if (act && lane != S_END) tEnd = trans[S_END * NK + lane];

    if (role == 0) {
        // ---------------- forward, exp-domain state
        float Erow[NK];
        {
            const bool rowdead = (lane == S_START);
            const float4* r4 = (const float4*)(trans + LL * NK);
            #pragma unroll
            for (int q = 0; q < NK / 4; ++q) {
                float4 r = r4[q];
                const int c = 4 * q;
                Erow[c + 0] = (rowdead || c + 0 == S_END) ? 0.0f : __expf(r.x);
                Erow[c + 1] = (rowdead || c + 1 == S_END) ? 0.0f : __expf(r.y);
                Erow[c + 2] = (rowdead || c + 2 == S_END) ? 0.0f : __expf(r.z);
                Erow[c + 3] = (rowdead || c + 3 == S_END) ? 0.0f : __expf(r.w);
            }
        }
        float ea = (lane == S_START) ? 1.0f : 0.0f;  // exp(alpha - M), anchored
        int Etot = 0;                                // exact binary exponent shift
        eabuf[lane] = ea;
        __builtin_amdgcn_wave_barrier();
        float fr0 = fb[0 * NK], fr1 = fb[1 * NK], fr2 = fb[2 * NK], fr3 = fb[3 * NK];

        auto fstep = [&](float fc) {
            float ef = __expf(fc);               // OFF-chain: fc ready 4 steps early
            float eav[NK];
            {
                const float4* e4 = (const float4*)eabuf;
                #pragma unroll
                for (int q = 0; q < NK / 4; ++q) {
                    float4 r = e4[q];
                    eav[4 * q + 0] = r.x; eav[4 * q + 1] = r.y;
                    eav[4 * q + 2] = r.z; eav[4 * q + 3] = r.w;
                }
            }
            float a0 = 0.f, a1 = 0.f, a2 = 0.f, a3 = 0.f;
            #pragma unroll
            for (int p = 0; p < NK; p += 4) {
                a0 = fmaf(Erow[p + 0], eav[p + 0], a0);
                a1 = fmaf(Erow[p + 1], eav[p + 1], a1);
                a2 = fmaf(Erow[p + 2], eav[p + 2], a2);
                a3 = fmaf(Erow[p + 3], eav[p + 3], a3);
            }
            float acc = (a0 + a1) + (a2 + a3);   // lane0: >0 always (ea[0]~1)
            float nv = acc * ef;                 // dead row: acc==0 -> stays 0
            float nvr = rfl_f32(nv);             // lane-0 value, positive normal
            int e = ((__float_as_int(nvr) >> 23) & 255) - 127;
            Etot += e;                           // exact integer accumulation
            float sc = __int_as_float((127 - e) << 23);  // exact 2^-e
            ea = nv * sc;                        // lane-0 back to [1,2)
            __builtin_amdgcn_wave_barrier();
            eabuf[lane] = ea;
            __builtin_amdgcn_wave_barrier();
        };

        __syncthreads();                                     // B0
        for (int it = 0; it <= NCH; ++it) {
            if (it < NCH) {
                for (int g = 0; g < CLEN / 4; ++g) {
                    const int t = it * CLEN + 4 * g;
                    { float fc = fr0; int nr = (t + 4 < NT) ? t + 4 : NT - 1; fr0 = fb[nr * NK]; fstep(fc); }
                    { float fc = fr1; int nr = (t + 5 < NT) ? t + 5 : NT - 1; fr1 = fb[nr * NK]; fstep(fc); }
                    { float fc = fr2; int nr = (t + 6 < NT) ? t + 6 : NT - 1; fr2 = fb[nr * NK]; fstep(fc); }
                    { float fc = fr3; int nr = (t + 7 < NT) ? t + 7 : NT - 1; fr3 = fb[nr * NK]; fstep(fc); }
                }
            }
            __syncthreads();                                 // B1..B33
        }
        // logZ = Etot*ln2 + logsumexp(log(ea) + tEnd)
        float u = __logf(ea);                    // ea==0 -> -inf (dead lanes)
        float x = act ? (u + tEnd) : -INFINITY;
        float M2 = x;
        #pragma unroll
        for (int off = 32; off >= 1; off >>= 1)
            M2 = fmaxf(M2, __shfl_xor(M2, off, 64));
        float es = __expf(x - M2);
        #pragma unroll
        for (int off = 32; off >= 1; off >>= 1)
            es += __shfl_xor(es, off, 64);
        if (lane == 0)
            out[b] = (float)Etot * 0.6931471805599453f + M2 + __logf(es);
    } else if (role == 1) {
        // ---------------- producer: value-only sweep + checkpoint ring
        float trow[NK];
        {
            const bool rowdead = (lane == S_START);
            const float4* r4 = (const float4*)(trans + LL * NK);
            #pragma unroll
            for (int q = 0; q < NK / 4; ++q) {
                float4 r = r4[q];
                const int c = 4 * q;
                trow[c + 0] = (rowdead || c + 0 == S_END) ? NEGV : r.x;
                trow[c + 1] = (rowdead || c + 1 == S_END) ? NEGV : r.y;
                trow[c + 2] = (rowdead || c + 2 == S_END) ? NEGV : r.z;
                trow[c + 3] = (rowdead || c + 3 == S_END) ? NEGV : r.w;
            }
        }
        float v = (lane == S_START) ? 0.0f : NEGV;
        vbuf1[lane] = v;
        if (act) ckpt[0 * NK + lane] = v;                    // chunk-0 entry
        __builtin_amdgcn_wave_barrier();
        float fr0 = fb[0 * NK], fr1 = fb[1 * NK], fr2 = fb[2 * NK], fr3 = fb[3 * NK];

        auto vstep = [&](float fc) {
            float s[NK];
            {
                const float4* v4 = (const float4*)vbuf1;
                #pragma unroll
                for (int q = 0; q < NK / 4; ++q) {
                    float4 r = v4[q];
                    s[4 * q + 0] = r.x + trow[4 * q + 0];
                    s[4 * q + 1] = r.y + trow[4 * q + 1];
                    s[4 * q + 2] = r.z + trow[4 * q + 2];
                    s[4 * q + 3] = r.w + trow[4 * q + 3];
                }
            }
            float m16[16];
            #pragma unroll
            for (int i = 0; i < 16; ++i)
                m16[i] = fmaxf(fmaxf(s[3 * i], s[3 * i + 1]), s[3 * i + 2]);
            float m6[6];
            #pragma unroll
            for (int i = 0; i < 5; ++i)
                m6[i] = fmaxf(fmaxf(m16[3 * i], m16[3 * i + 1]), m16[3 * i + 2]);
            m6[5] = m16[15];
            float best = fmaxf(fmaxf(fmaxf(m6[0], m6[1]), m6[2]),
                               fmaxf(fmaxf(m6[3], m6[4]), m6[5]));
            v = best + fc;                                   // +feat after max
            __builtin_amdgcn_wave_barrier();
            vbuf1[lane] = v;
            __builtin_amdgcn_wave_barrier();
        };

        int last = 0;
        __syncthreads();                                     // B0
        for (int it = 0; it <= NCH; ++it) {
            if (it < NCH) {
                for (int g = 0; g < CLEN / 4; ++g) {
                    const int t = it * CLEN + 4 * g;
                    { float fc = fr0; int nr = (t + 4 < NT) ? t + 4 : NT - 1; fr0 = fb[nr * NK]; vstep(fc); }
                    { float fc = fr1; int nr = (t + 5 < NT) ? t + 5 : NT - 1; fr1 = fb[nr * NK]; vstep(fc); }
                    { float fc = fr2; int nr = (t + 6 < NT) ? t + 6 : NT - 1; fr2 = fb[nr * NK]; vstep(fc); }
                    { float fc = fr3; int nr = (t + 7 < NT) ? t + 7 : NT - 1; fr3 = fb[nr * NK]; vstep(fc); }
                }
                // v is now the entry state of chunk it+1 -> ring slot
                if (act && it + 1 < NCH) ckpt[((it + 1) & 3) * NK + lane] = v;
            } else {
                // termination: first-occurrence argmax of v + trans[END]
                float xv = act ? (v + tEnd) : -INFINITY;
                int idx = act ? lane : 63;
                float val = xv;
                #pragma unroll
                for (int off = 32; off >= 1; off >>= 1) {
                    float ov = __shfl_xor(val, off, 64);
                    int   oi = __shfl_xor(idx, off, 64);
                    if (ov > val || (ov == val && oi < idx)) { val = ov; idx = oi; }
                }
                if (lane == 0) out[NB + b] = val;
                last = idx;
            }
            __syncthreads();                                 // B1..B33
        }
        // epilogue: chase + expansion (bp/comp complete after final barrier)
        if (lane == 0) {
            int tag = last;
            for (int l = NCH - 1; l >= 0; --l) {
                boundary[l] = (unsigned char)tag;
                tag = comp[l * NK + tag];
            }
        }
        __builtin_amdgcn_wave_barrier();
        if (lane < NCH) {
            int tag = boundary[lane];                        // lane = chunk
            float* pout = out + 2 * NB + (size_t)b * NT;
            const int tbase = lane * CLEN;
            for (int i = CLEN - 1; i >= 0; --i) {
                pout[tbase + i] = (float)tag;
                tag = bp[(tbase + i) * NK + tag];
            }
        }
    } else {
        // ---------------- consumers: replay chunk c over windows c, c+1
        const int w = role - 2;                              // 0: even, 1: odd
        float trow[NK];
        {
            const bool rowdead = (lane == S_START);
            const float4* r4 = (const float4*)(trans + LL * NK);
            #pragma unroll
            for (int q = 0; q < NK / 4; ++q) {
                float4 r = r4[q];
                const int c = 4 * q;
                trow[c + 0] = (rowdead || c + 0 == S_END) ? NEGV : r.x;
                trow[c + 1] = (rowdead || c + 1 == S_END) ? NEGV : r.y;
                trow[c + 2] = (rowdead || c + 2 == S_END) ? NEGV : r.z;
                trow[c + 3] = (rowdead || c + 3 == S_END) ? NEGV : r.w;
            }
        }
        float* vbw = vbufw[w];
        const int big = 63;
        int bpl[16], bph[16];

        // 16 replay steps [base, base+16) of chunk c; ba statically indexed
        auto replay16 = [&](int c, int base, int* ba) {
            const float* fbc = fb + (size_t)c * CLEN * NK;
            unsigned char* bpc = bp + (size_t)c * CLEN * NK;
            float fv[16];
            #pragma unroll
            for (int i = 0; i < 16; ++i) fv[i] = fbc[(base + i) * NK];
            #pragma unroll
            for (int i = 0; i < 16; ++i) {
                float s[NK];
                {
                    const float4* v4 = (const float4*)vbw;
                    #pragma unroll
                    for (int q = 0; q < NK / 4; ++q) {
                        float4 r = v4[q];
                        s[4 * q + 0] = r.x + trow[4 * q + 0];
                        s[4 * q + 1] = r.y + trow[4 * q + 1];
                        s[4 * q + 2] = r.z + trow[4 * q + 2];
                        s[4 * q + 3] = r.w + trow[4 * q + 3];
                    }
                }
                float m16[16];
                #pragma unroll
                for (int j = 0; j < 16; ++j)
                    m16[j] = fmaxf(fmaxf(s[3 * j], s[3 * j + 1]), s[3 * j + 2]);
                float m6[6];
                #pragma unroll
                for (int j = 0; j < 5; ++j)
                    m6[j] = fmaxf(fmaxf(m16[3 * j], m16[3 * j + 1]), m16[3 * j + 2]);
                m6[5] = m16[15];
                float best = fmaxf(fmaxf(fmaxf(m6[0], m6[1]), m6[2]),
                                   fmaxf(fmaxf(m6[3], m6[4]), m6[5]));
                // first-occurrence argmax: chained select per 3-wide group
                int n16[16];
                #pragma unroll
                for (int j = 0; j < 16; ++j) {
                    int r = (s[3 * j + 2] == best) ? 3 * j + 2 : big;
                    r = (s[3 * j + 1] == best) ? 3 * j + 1 : r;
                    r = (s[3 * j + 0] == best) ? 3 * j + 0 : r;
                    n16[j] = r;
                }
                int n6[6];
                #pragma unroll
                for (int j = 0; j < 5; ++j)
                    n6[j] = min(min(n16[3 * j], n16[3 * j + 1]), n16[3 * j + 2]);
                n6[5] = n16[15];
                int bi = min(min(min(n6[0], n6[1]), n6[2]),
                             min(min(n6[3], n6[4]), n6[5]));

                ba[i] = bi;
                bpc[(base + i) * NK + LL] = (unsigned char)bi;
                float vn = best + fv[i];                     // +feat after argmax
                __builtin_amdgcn_wave_barrier();
                vbw[lane] = vn;
                __builtin_amdgcn_wave_barrier();
            }
        };

        __syncthreads();                                     // B0
        for (int it = 0; it <= NCH; ++it) {
            if (it < NCH && (it & 1) == w) {
                // start chunk c = it (ckpt[c] published during window it-1)
                vbw[lane] = ckpt[(it & 3) * NK + LL];
                __builtin_amdgcn_wave_barrier();
                replay16(it, 0, bpl);
            } else if (it >= 1 && ((it - 1) & 1) == w) {
                // finish chunk c = it-1, then compose its tag-map
                const int c = it - 1;
                replay16(c, 16, bph);
                int tag = act ? lane : 0;
                #pragma unroll
                for (int i = 15; i >= 0; --i)
                    tag = __builtin_amdgcn_ds_bpermute(tag << 2, bph[i]);
                #pragma unroll
                for (int i = 15; i >= 0; --i)
                    tag = __builtin_amdgcn_ds_bpermute(tag << 2, bpl[i]);
                if (act) comp[c * NK + lane] = (unsigned char)tag;
            }
            __syncthreads();                                 // B1..B33
        }
    }
}

extern "C" void kernel_launch(void* const* d_in, const int* in_sizes, int n_in,
                              void* d_out, int out_size, void* d_ws, size_t ws_size,
                              hipStream_t stream) {
    (void)in_sizes; (void)n_in; (void)d_ws; (void)ws_size; (void)out_size;
    const float* feats = (const float*)d_in[0];
    const float* trans = (const float*)d_in[1];
    float* out = (float*)d_out;
    crf_fused<<<dim3(NB), dim3(256), 0, stream>>>(feats, trans, out);
}